// Round 12
// baseline (266.658 us; speedup 1.0000x reference)
//
#include <hip/hip_runtime.h>

#define NN 100000
#define EE 1600000
#define CH 128

typedef _Float16 h2 __attribute__((ext_vector_type(2)));
typedef _Float16 h8 __attribute__((ext_vector_type(8)));
typedef float f32x4 __attribute__((ext_vector_type(4)));

// bucketed CSR build params
#define S_NODES 512
#define NBUCK 196
#define CAP_E 10240

// 2-way channel-sliced feature layout: element (n, ch) lives at
//   [ (ch>>6) * (NN*64) + n*64 + (ch&63) ]
#define SLICE_STRIDE ((size_t)NN * 64)

// ---------------- Pass A: partition edges into dst-buckets ----------------

__global__ __launch_bounds__(256) void k_passA(const int* __restrict__ src, const int* __restrict__ dst,
                                               int* __restrict__ gcur, int* __restrict__ eb) {
    __shared__ int hist[NBUCK];
    __shared__ int curL[NBUCK];
    for (int t = threadIdx.x; t < NBUCK; t += 256) hist[t] = 0;
    __syncthreads();
    int base = blockIdx.x * 4096;
    int pk[16], bk[16];
#pragma unroll
    for (int j = 0; j < 16; ++j) {
        int i = base + threadIdx.x + 256 * j;
        if (i < EE) {
            int s = src[i], d = dst[i];
            bk[j] = d >> 9;
            pk[j] = (s << 9) | (d & 511);
            atomicAdd(&hist[bk[j]], 1);
        } else bk[j] = -1;
    }
    __syncthreads();
    for (int t = threadIdx.x; t < NBUCK; t += 256) {
        int h = hist[t];
        curL[t] = (h > 0) ? atomicAdd(&gcur[t], h) : 0;
    }
    __syncthreads();
#pragma unroll
    for (int j = 0; j < 16; ++j) {
        if (bk[j] >= 0) {
            int pos = atomicAdd(&curL[bk[j]], 1);
            if (pos < CAP_E) eb[bk[j] * CAP_E + pos] = pk[j];
        }
    }
}

// ---------------- fused bucket-base scan + weight/BN prep ----------------

__global__ __launch_bounds__(256) void k_bscan_prep(const int* __restrict__ gcur, int* __restrict__ bbase,
                                                    int* __restrict__ rp,
                                                    const float* __restrict__ W1, const float* __restrict__ W2,
                                                    _Float16* __restrict__ Wt1, _Float16* __restrict__ Wt2,
                                                    const float* __restrict__ b1, const float* __restrict__ g1,
                                                    const float* __restrict__ be1, const float* __restrict__ rm1,
                                                    const float* __restrict__ rv1,
                                                    const float* __restrict__ b2, const float* __restrict__ g2,
                                                    const float* __restrict__ be2, const float* __restrict__ rm2,
                                                    const float* __restrict__ rv2,
                                                    float* __restrict__ sc1, float* __restrict__ sh1,
                                                    float* __restrict__ sc2, float* __restrict__ sh2) {
    int bid = blockIdx.x, tid = threadIdx.x;
    if (bid == 0) {
        __shared__ int ts[256];
        int nn = (tid < NBUCK) ? min(S_NODES, NN - tid * S_NODES) : 0;
        int v = (tid < NBUCK) ? (min(gcur[tid], CAP_E) + nn) : 0;
        ts[tid] = v; __syncthreads();
        for (int off = 1; off < 256; off <<= 1) {
            int u = (tid >= off) ? ts[tid - off] : 0;
            __syncthreads();
            ts[tid] += u;
            __syncthreads();
        }
        if (tid < NBUCK) bbase[tid] = ts[tid] - v;
        if (tid == 0) rp[NN] = EE + NN;
    } else if (bid <= 64) {
        int r = (bid - 1) * 2 + (tid >> 7);
        int k = tid & 127;
        Wt1[r * 128 + k] = (_Float16)W1[k * 128 + r];
    } else if (bid <= 128) {
        int r = (bid - 65) * 2 + (tid >> 7);
        int k = tid & 127;
        Wt2[r * 128 + k] = (_Float16)W2[k * 128 + r];
    } else {
        if (tid < 128) {
            float sv = g1[tid] * rsqrtf(rv1[tid] + 1e-5f);
            sc1[tid] = sv;
            sh1[tid] = (b1[tid] - rm1[tid]) * sv + be1[tid];
        } else {
            int t = tid - 128;
            float sv = g2[t] * rsqrtf(rv2[t] + 1e-5f);
            sc2[t] = sv;
            sh2[t] = (b2[t] - rm2[t]) * sv + be2[t];
        }
    }
}

// ---------------- fused Pass B ----------------

__global__ __launch_bounds__(256) void k_passB(const int* __restrict__ gcur, const int* __restrict__ eb,
                                               const int* __restrict__ bbase, int* __restrict__ rp,
                                               float* __restrict__ dinv, int* __restrict__ col) {
    __shared__ int c[S_NODES];
    __shared__ int excl[S_NODES];
    __shared__ int cur[S_NODES];
    __shared__ int ts[256];
    __shared__ int stage[CAP_E + S_NODES];
    int bId = blockIdx.x;
    int nbase = bId * S_NODES;
    int tid = threadIdx.x;
    c[tid] = 0; c[tid + 256] = 0;
    __syncthreads();
    int n = min(gcur[bId], CAP_E);
    const int* e = eb + (size_t)bId * CAP_E;
    for (int i = tid; i < n; i += 256) atomicAdd(&c[e[i] & 511], 1);
    __syncthreads();
    int n0 = nbase + 2 * tid, n1 = n0 + 1;
    int v0 = (n0 < NN) ? c[2 * tid] + 1 : 0;
    int v1 = (n1 < NN) ? c[2 * tid + 1] + 1 : 0;
    int s = v0 + v1;
    ts[tid] = s; __syncthreads();
    for (int off = 1; off < 256; off <<= 1) {
        int u = (tid >= off) ? ts[tid - off] : 0;
        __syncthreads();
        ts[tid] += u;
        __syncthreads();
    }
    int ex = ts[tid] - s;
    int base = bbase[bId];
    excl[2 * tid] = ex; excl[2 * tid + 1] = ex + v0;
    cur[2 * tid] = ex;  cur[2 * tid + 1] = ex + v0;
    if (n0 < NN) { rp[n0] = base + ex;      dinv[n0] = rsqrtf((float)v0); }
    if (n1 < NN) { rp[n1] = base + ex + v0; dinv[n1] = rsqrtf((float)v1); }
    __syncthreads();
    for (int i = tid; i < n; i += 256) {
        int pe = e[i];
        int pos = atomicAdd(&cur[pe & 511], 1);
        stage[pos] = pe >> 9;
    }
    {
        int t0 = 2 * tid, t1 = 2 * tid + 1;
        if (n0 < NN) stage[excl[t0] + c[t0]] = n0;
        if (n1 < NN) stage[excl[t1] + c[t1]] = n1;
    }
    __syncthreads();
    int total = ts[255];
    for (int i = tid; i < total; i += 256) col[base + i] = stage[i];
}

// ---------------- MFMA GEMM [N,128]@[128,128], epilogue row*=dinv, out fp16 SLICED ----

template <bool F32IN>
__global__ __launch_bounds__(256) void k_gemm_mfma(const void* __restrict__ Ain,
                                                   const _Float16* __restrict__ Wt,
                                                   const float* __restrict__ dinv,
                                                   _Float16* __restrict__ C) {
    __shared__ _Float16 Wl[CH * CH];  // 32 KB, [row][16B-slot XOR-swizzled]
    {
        const float4* wg = (const float4*)Wt;
#pragma unroll
        for (int i = 0; i < 8; ++i) {
            int chunk = i * 256 + threadIdx.x;
            int row = chunk >> 4, slot = chunk & 15;
            float4 v = wg[chunk];
            *(float4*)((char*)Wl + row * 256 + ((slot ^ (row & 15)) * 16)) = v;
        }
    }
    __syncthreads();
    int lane = threadIdx.x & 63;
    int l15 = lane & 15, lhi = lane >> 4;
    int row0 = blockIdx.x * 64 + (threadIdx.x >> 6) * 16;
    if (row0 >= NN) return;

    h8 afrag[4];
    if (F32IN) {
        const float* Arow = (const float*)Ain + (size_t)(row0 + l15) * CH + lhi * 8;
#pragma unroll
        for (int ks = 0; ks < 4; ++ks) {
            float4 a = *(const float4*)(Arow + ks * 32);
            float4 b = *(const float4*)(Arow + ks * 32 + 4);
            h8 o;
            o[0] = (_Float16)a.x; o[1] = (_Float16)a.y; o[2] = (_Float16)a.z; o[3] = (_Float16)a.w;
            o[4] = (_Float16)b.x; o[5] = (_Float16)b.y; o[6] = (_Float16)b.z; o[7] = (_Float16)b.w;
            afrag[ks] = o;
        }
    } else {
        const _Float16* Ah = (const _Float16*)Ain;
#pragma unroll
        for (int ks = 0; ks < 4; ++ks) {
            int ch = ks * 32 + lhi * 8;
            afrag[ks] = *(const h8*)(Ah + (size_t)(ch >> 6) * SLICE_STRIDE
                                     + (size_t)(row0 + l15) * 64 + (ch & 63));
        }
    }

    f32x4 acc[8] = {};
#pragma unroll
    for (int ks = 0; ks < 4; ++ks) {
        int slot = ks * 4 + lhi;
#pragma unroll
        for (int c = 0; c < 8; ++c) {
            int brow = c * 16 + l15;
            h8 b = *(const h8*)((char*)Wl + brow * 256 + ((slot ^ (brow & 15)) * 16));
            acc[c] = __builtin_amdgcn_mfma_f32_16x16x32_f16(afrag[ks], b, acc[c], 0, 0, 0);
        }
    }
    float dv[4];
#pragma unroll
    for (int j = 0; j < 4; ++j) dv[j] = dinv[row0 + lhi * 4 + j];
#pragma unroll
    for (int c = 0; c < 8; ++c) {
        int colIdx = c * 16 + l15;
        _Float16* Cd = C + (size_t)(colIdx >> 6) * SLICE_STRIDE + (colIdx & 63);
#pragma unroll
        for (int j = 0; j < 4; ++j) {
            float v = acc[c][j] * dv[j];
            Cd[(size_t)(row0 + lhi * 4 + j) * 64] = (_Float16)v;
        }
    }
}

// ---------------- 2-way sliced aggregation (R4 instruction economy) ----------------
// slice = blockIdx&1; round-robin block->XCD => XCDs {0,2,4,6} only touch slice 0,
// {1,3,5,7} only slice 1 => per-XCD compulsory table fetch halves (194->~118 MB).
// Wave = 1 node; lanes pair two edges per gather instr (esub = lane>>5 picks edge,
// cp = lane&31 picks ch-pair): 256 B/instr, same gather-instr count as R4.
// Uniform scalar col loads; one shfl_xor(32) epilogue combines edge-halves.

__global__ __launch_bounds__(256) void k_aggs6(const _Float16* __restrict__ h, const int* __restrict__ rp,
                                               const int* __restrict__ col, const float* __restrict__ dinv,
                                               const float* __restrict__ sc, const float* __restrict__ sh,
                                               _Float16* __restrict__ out) {
    int slice = blockIdx.x & 1;
    int node = (blockIdx.x >> 1) * 4 + (threadIdx.x >> 6);
    if (node >= NN) return;
    node = __builtin_amdgcn_readfirstlane(node);
    int lane = threadIdx.x & 63;
    int esub = lane >> 5;
    int cp = lane & 31;
    int beg = rp[node], end = rp[node + 1];
    const _Float16* hs = h + (size_t)slice * SLICE_STRIDE;
    float ax = 0.f, ay = 0.f, bx = 0.f, by = 0.f;
    int e = beg;
    for (; e + 8 <= end; e += 8) {
        int s0 = col[e],     s1 = col[e + 1], s2 = col[e + 2], s3 = col[e + 3];
        int s4 = col[e + 4], s5 = col[e + 5], s6 = col[e + 6], s7 = col[e + 7];
        int i0 = esub ? s1 : s0;
        int i1 = esub ? s3 : s2;
        int i2 = esub ? s5 : s4;
        int i3 = esub ? s7 : s6;
        h2 v0 = *(const h2*)(hs + (size_t)i0 * 64 + cp * 2);
        h2 v1 = *(const h2*)(hs + (size_t)i1 * 64 + cp * 2);
        h2 v2 = *(const h2*)(hs + (size_t)i2 * 64 + cp * 2);
        h2 v3 = *(const h2*)(hs + (size_t)i3 * 64 + cp * 2);
        ax += (float)v0[0] + (float)v1[0];
        ay += (float)v0[1] + (float)v1[1];
        bx += (float)v2[0] + (float)v3[0];
        by += (float)v2[1] + (float)v3[1];
    }
    for (; e + 2 <= end; e += 2) {
        int s0 = col[e], s1 = col[e + 1];
        int i0 = esub ? s1 : s0;
        h2 v0 = *(const h2*)(hs + (size_t)i0 * 64 + cp * 2);
        ax += (float)v0[0];
        ay += (float)v0[1];
    }
    if (e < end) {
        int s0 = col[e];
        h2 v0 = *(const h2*)(hs + (size_t)s0 * 64 + cp * 2);
        float m = (esub == 0) ? 1.f : 0.f;
        ax = fmaf((float)v0[0], m, ax);
        ay = fmaf((float)v0[1], m, ay);
    }
    ax += bx; ay += by;
    ax += __shfl_xor(ax, 32);
    ay += __shfl_xor(ay, 32);
    if (esub == 0) {
        float dvn = dinv[node];
        int c = slice * 64 + cp * 2;
        float2 scv = *(const float2*)(sc + c);
        float2 shv = *(const float2*)(sh + c);
        float o0 = fmaxf(fmaf(ax * dvn, scv.x, shv.x), 0.f);
        float o1 = fmaxf(fmaf(ay * dvn, scv.y, shv.y), 0.f);
        h2 o; o[0] = (_Float16)o0; o[1] = (_Float16)o1;
        *(h2*)(out + (size_t)slice * SLICE_STRIDE + (size_t)node * 64 + cp * 2) = o;
    }
}

// ---------------- Layer 3 (reads sliced layout) ----------------

__global__ __launch_bounds__(256) void k_gemm_out(const _Float16* __restrict__ A, const float* __restrict__ W3,
                                                  const float* __restrict__ dinv, float* __restrict__ H3) {
    __shared__ float w3s[256];
    w3s[threadIdx.x] = W3[threadIdx.x];
    __syncthreads();
    int n = blockIdx.x * 256 + threadIdx.x;
    if (n >= NN) return;
    float a0 = 0.f, a1 = 0.f;
#pragma unroll
    for (int kb = 0; kb < 16; ++kb) {
        int ch = kb * 8;
        h8 a = *(const h8*)(A + (size_t)(ch >> 6) * SLICE_STRIDE + (size_t)n * 64 + (ch & 63));
#pragma unroll
        for (int j = 0; j < 8; ++j) {
            float av = (float)a[j];
            int k = ch + j;
            a0 += av * w3s[k * 2];
            a1 += av * w3s[k * 2 + 1];
        }
    }
    float dv = dinv[n];
    *(float2*)(H3 + (size_t)n * 2) = make_float2(a0 * dv, a1 * dv);
}

__global__ __launch_bounds__(256) void k_agg_out(const float* __restrict__ H3, const int* __restrict__ rp,
                                                 const int* __restrict__ col, const float* __restrict__ dinv,
                                                 const float* __restrict__ b3, float* __restrict__ out) {
    int n = blockIdx.x * 256 + threadIdx.x;
    if (n >= NN) return;
    int beg = rp[n], end = rp[n + 1];
    float a0 = 0.f, a1 = 0.f;
    for (int e = beg; e < end; ++e) {
        int s = col[e];
        float2 hv = *(const float2*)(H3 + (size_t)s * 2);
        a0 += hv.x;
        a1 += hv.y;
    }
    float dv = dinv[n];
    out[(size_t)n * 2 + 0] = fmaf(a0, dv, b3[0]);
    out[(size_t)n * 2 + 1] = fmaf(a1, dv, b3[1]);
}

// ---------------- launch ----------------

extern "C" void kernel_launch(void* const* d_in, const int* in_sizes, int n_in,
                              void* d_out, int out_size, void* d_ws, size_t ws_size,
                              hipStream_t stream) {
    const float* x  = (const float*)d_in[0];
    const int* ei   = (const int*)d_in[1];
    const int* src  = ei;
    const int* dst  = ei + EE;
    const float* W1 = (const float*)d_in[2];
    const float* b1 = (const float*)d_in[3];
    const float* g1 = (const float*)d_in[4];
    const float* be1 = (const float*)d_in[5];
    const float* rm1 = (const float*)d_in[6];
    const float* rv1 = (const float*)d_in[7];
    const float* W2 = (const float*)d_in[8];
    const float* b2 = (const float*)d_in[9];
    const float* g2 = (const float*)d_in[10];
    const float* be2 = (const float*)d_in[11];
    const float* rm2 = (const float*)d_in[12];
    const float* rv2 = (const float*)d_in[13];
    const float* W3 = (const float*)d_in[14];
    const float* b3 = (const float*)d_in[15];
    float* out = (float*)d_out;

    char* p = (char*)d_ws;
    auto carve = [&](size_t bytes) -> void* {
        void* r = (void*)p;
        p += (bytes + 255) & ~(size_t)255;
        return r;
    };
    int* rp     = (int*)carve((size_t)(NN + 1) * 4);
    float* dinv = (float*)carve((size_t)NN * 4);
    int* col    = (int*)carve((size_t)(EE + NN) * 4);
    int* bbase  = (int*)carve(256 * 4);
    float* sc1  = (float*)carve(128 * 4);
    float* sh1  = (float*)carve(128 * 4);
    float* sc2  = (float*)carve(128 * 4);
    float* sh2  = (float*)carve(128 * 4);
    _Float16* bufA = (_Float16*)carve((size_t)NN * CH * 2);
    _Float16* bufB = (_Float16*)carve((size_t)NN * CH * 2);
    _Float16* Wt1  = (_Float16*)carve(128 * 128 * 2);
    _Float16* Wt2  = (_Float16*)carve(128 * 128 * 2);
    float* h3   = (float*)carve((size_t)NN * 2 * 4);

    // bucket workspace aliases bufA (dead until first GEMM): 8.03 MB < 25.6 MB
    int* eb   = (int*)bufA;
    int* gcur = eb + (size_t)NBUCK * CAP_E;

    hipMemsetAsync(gcur, 0, (size_t)NBUCK * 4, stream);

    k_passA<<<(EE + 4095) / 4096, 256, 0, stream>>>(src, dst, gcur, eb);
    k_bscan_prep<<<130, 256, 0, stream>>>(gcur, bbase, rp,
                                          W1, W2, Wt1, Wt2,
                                          b1, g1, be1, rm1, rv1,
                                          b2, g2, be2, rm2, rv2,
                                          sc1, sh1, sc2, sh2);
    k_passB<<<NBUCK, 256, 0, stream>>>(gcur, eb, bbase, rp, dinv, col);

    int aggBlocks = 2 * ((NN + 3) / 4);
    k_gemm_mfma<true><<<(NN + 63) / 64, 256, 0, stream>>>(x, Wt1, dinv, bufA);
    k_aggs6<<<aggBlocks, 256, 0, stream>>>(bufA, rp, col, dinv, sc1, sh1, bufB);
    k_gemm_mfma<false><<<(NN + 63) / 64, 256, 0, stream>>>(bufB, Wt2, dinv, bufA);
    k_aggs6<<<aggBlocks, 256, 0, stream>>>(bufA, rp, col, dinv, sc2, sh2, bufB);
    k_gemm_out<<<(NN + 255) / 256, 256, 0, stream>>>(bufB, W3, dinv, h3);
    k_agg_out<<<(NN + 255) / 256, 256, 0, stream>>>(h3, rp, col, dinv, b3, out);
}

// Round 13
// 216.087 us; speedup vs baseline: 1.2340x; 1.2340x over previous
//
#include <hip/hip_runtime.h>

#define NN 100000
#define EE 1600000
#define CH 128

typedef _Float16 h2 __attribute__((ext_vector_type(2)));
typedef _Float16 h8 __attribute__((ext_vector_type(8)));
typedef float f32x4 __attribute__((ext_vector_type(4)));

// bucketed CSR build params
#define S_NODES 512
#define NBUCK 196
#define CAP_E 10240

// ---------------- Pass A: partition edges into dst-buckets ----------------
// Packed entry = (src<<9) | (dst & 511). 16 consecutive edges/thread via int4.

__global__ __launch_bounds__(256) void k_passA(const int* __restrict__ src, const int* __restrict__ dst,
                                               int* __restrict__ gcur, int* __restrict__ eb) {
    __shared__ int hist[NBUCK];
    __shared__ int curL[NBUCK];
    for (int t = threadIdx.x; t < NBUCK; t += 256) hist[t] = 0;
    __syncthreads();
    int base = blockIdx.x * 4096 + threadIdx.x * 16;
    int pk[16], bk[16];
    if (base < EE) {   // EE % 16 == 0: chunk fully valid or fully invalid
        const int4* sv = (const int4*)(src + base);
        const int4* dv = (const int4*)(dst + base);
#pragma unroll
        for (int q = 0; q < 4; ++q) {
            int4 s4 = sv[q], d4 = dv[q];
            int j = q * 4;
            bk[j + 0] = d4.x >> 9; pk[j + 0] = (s4.x << 9) | (d4.x & 511);
            bk[j + 1] = d4.y >> 9; pk[j + 1] = (s4.y << 9) | (d4.y & 511);
            bk[j + 2] = d4.z >> 9; pk[j + 2] = (s4.z << 9) | (d4.z & 511);
            bk[j + 3] = d4.w >> 9; pk[j + 3] = (s4.w << 9) | (d4.w & 511);
        }
#pragma unroll
        for (int j = 0; j < 16; ++j) atomicAdd(&hist[bk[j]], 1);
    } else {
#pragma unroll
        for (int j = 0; j < 16; ++j) bk[j] = -1;
    }
    __syncthreads();
    for (int t = threadIdx.x; t < NBUCK; t += 256) {
        int h = hist[t];
        curL[t] = (h > 0) ? atomicAdd(&gcur[t], h) : 0;
    }
    __syncthreads();
#pragma unroll
    for (int j = 0; j < 16; ++j) {
        if (bk[j] >= 0) {
            int pos = atomicAdd(&curL[bk[j]], 1);
            if (pos < CAP_E) eb[bk[j] * CAP_E + pos] = pk[j];
        }
    }
}

// ---------------- fused bucket-base scan + weight/BN prep ----------------
// block 0: exclusive scan of bucket totals -> bbase, rp[NN]
// blocks 1..64: W1^T fp16 (2 rows/block); 65..128: W2^T; 129: BN folds.

__global__ __launch_bounds__(256) void k_bscan_prep(const int* __restrict__ gcur, int* __restrict__ bbase,
                                                    int* __restrict__ rp,
                                                    const float* __restrict__ W1, const float* __restrict__ W2,
                                                    _Float16* __restrict__ Wt1, _Float16* __restrict__ Wt2,
                                                    const float* __restrict__ b1, const float* __restrict__ g1,
                                                    const float* __restrict__ be1, const float* __restrict__ rm1,
                                                    const float* __restrict__ rv1,
                                                    const float* __restrict__ b2, const float* __restrict__ g2,
                                                    const float* __restrict__ be2, const float* __restrict__ rm2,
                                                    const float* __restrict__ rv2,
                                                    float* __restrict__ sc1, float* __restrict__ sh1,
                                                    float* __restrict__ sc2, float* __restrict__ sh2) {
    int bid = blockIdx.x, tid = threadIdx.x;
    if (bid == 0) {
        __shared__ int ts[256];
        int nn = (tid < NBUCK) ? min(S_NODES, NN - tid * S_NODES) : 0;
        int v = (tid < NBUCK) ? (min(gcur[tid], CAP_E) + nn) : 0;
        ts[tid] = v; __syncthreads();
        for (int off = 1; off < 256; off <<= 1) {
            int u = (tid >= off) ? ts[tid - off] : 0;
            __syncthreads();
            ts[tid] += u;
            __syncthreads();
        }
        if (tid < NBUCK) bbase[tid] = ts[tid] - v;
        if (tid == 0) rp[NN] = EE + NN;
    } else if (bid <= 64) {
        int r = (bid - 1) * 2 + (tid >> 7);
        int k = tid & 127;
        Wt1[r * 128 + k] = (_Float16)W1[k * 128 + r];
    } else if (bid <= 128) {
        int r = (bid - 65) * 2 + (tid >> 7);
        int k = tid & 127;
        Wt2[r * 128 + k] = (_Float16)W2[k * 128 + r];
    } else {
        if (tid < 128) {
            float sv = g1[tid] * rsqrtf(rv1[tid] + 1e-5f);
            sc1[tid] = sv;
            sh1[tid] = (b1[tid] - rm1[tid]) * sv + be1[tid];
        } else {
            int t = tid - 128;
            float sv = g2[t] * rsqrtf(rv2[t] + 1e-5f);
            sc2[t] = sv;
            sh2[t] = (b2[t] - rm2[t]) * sv + be2[t];
        }
    }
}

// ---------------- fused Pass B: count + local scan + rp/dinv + place + dump ----------------

__global__ __launch_bounds__(256) void k_passB(const int* __restrict__ gcur, const int* __restrict__ eb,
                                               const int* __restrict__ bbase, int* __restrict__ rp,
                                               float* __restrict__ dinv, int* __restrict__ col) {
    __shared__ int c[S_NODES];
    __shared__ int excl[S_NODES];
    __shared__ int cur[S_NODES];
    __shared__ int ts[256];
    __shared__ int stage[CAP_E + S_NODES];
    int bId = blockIdx.x;
    int nbase = bId * S_NODES;
    int tid = threadIdx.x;
    c[tid] = 0; c[tid + 256] = 0;
    __syncthreads();
    int n = min(gcur[bId], CAP_E);
    const int* e = eb + (size_t)bId * CAP_E;
    for (int i = tid; i < n; i += 256) atomicAdd(&c[e[i] & 511], 1);
    __syncthreads();
    int n0 = nbase + 2 * tid, n1 = n0 + 1;
    int v0 = (n0 < NN) ? c[2 * tid] + 1 : 0;
    int v1 = (n1 < NN) ? c[2 * tid + 1] + 1 : 0;
    int s = v0 + v1;
    ts[tid] = s; __syncthreads();
    for (int off = 1; off < 256; off <<= 1) {
        int u = (tid >= off) ? ts[tid - off] : 0;
        __syncthreads();
        ts[tid] += u;
        __syncthreads();
    }
    int ex = ts[tid] - s;
    int base = bbase[bId];
    excl[2 * tid] = ex; excl[2 * tid + 1] = ex + v0;
    cur[2 * tid] = ex;  cur[2 * tid + 1] = ex + v0;
    if (n0 < NN) { rp[n0] = base + ex;      dinv[n0] = rsqrtf((float)v0); }
    if (n1 < NN) { rp[n1] = base + ex + v0; dinv[n1] = rsqrtf((float)v1); }
    __syncthreads();
    for (int i = tid; i < n; i += 256) {
        int pe = e[i];
        int pos = atomicAdd(&cur[pe & 511], 1);
        stage[pos] = pe >> 9;
    }
    {
        int t0 = 2 * tid, t1 = 2 * tid + 1;
        if (n0 < NN) stage[excl[t0] + c[t0]] = n0;
        if (n1 < NN) stage[excl[t1] + c[t1]] = n1;
    }
    __syncthreads();
    int total = ts[255];
    for (int i = tid; i < total; i += 256) col[base + i] = stage[i];
}

// ---------------- MFMA GEMM [N,128]@[128,128], epilogue row*=dinv, out fp16 row-major ----

template <bool F32IN>
__global__ __launch_bounds__(256) void k_gemm_mfma(const void* __restrict__ Ain,
                                                   const _Float16* __restrict__ Wt,
                                                   const float* __restrict__ dinv,
                                                   _Float16* __restrict__ C) {
    __shared__ _Float16 Wl[CH * CH];  // 32 KB, [row][16B-slot XOR-swizzled]
    {
        const float4* wg = (const float4*)Wt;
#pragma unroll
        for (int i = 0; i < 8; ++i) {
            int chunk = i * 256 + threadIdx.x;
            int row = chunk >> 4, slot = chunk & 15;
            float4 v = wg[chunk];
            *(float4*)((char*)Wl + row * 256 + ((slot ^ (row & 15)) * 16)) = v;
        }
    }
    __syncthreads();
    int lane = threadIdx.x & 63;
    int l15 = lane & 15, lhi = lane >> 4;
    int row0 = blockIdx.x * 64 + (threadIdx.x >> 6) * 16;
    if (row0 >= NN) return;

    h8 afrag[4];
    if (F32IN) {
        const float* Arow = (const float*)Ain + (size_t)(row0 + l15) * CH + lhi * 8;
#pragma unroll
        for (int ks = 0; ks < 4; ++ks) {
            float4 a = *(const float4*)(Arow + ks * 32);
            float4 b = *(const float4*)(Arow + ks * 32 + 4);
            h8 o;
            o[0] = (_Float16)a.x; o[1] = (_Float16)a.y; o[2] = (_Float16)a.z; o[3] = (_Float16)a.w;
            o[4] = (_Float16)b.x; o[5] = (_Float16)b.y; o[6] = (_Float16)b.z; o[7] = (_Float16)b.w;
            afrag[ks] = o;
        }
    } else {
        const _Float16* Arow = (const _Float16*)Ain + (size_t)(row0 + l15) * CH + lhi * 8;
#pragma unroll
        for (int ks = 0; ks < 4; ++ks) afrag[ks] = *(const h8*)(Arow + ks * 32);
    }

    f32x4 acc[8] = {};
#pragma unroll
    for (int ks = 0; ks < 4; ++ks) {
        int slot = ks * 4 + lhi;
#pragma unroll
        for (int c = 0; c < 8; ++c) {
            int brow = c * 16 + l15;
            h8 b = *(const h8*)((char*)Wl + brow * 256 + ((slot ^ (brow & 15)) * 16));
            acc[c] = __builtin_amdgcn_mfma_f32_16x16x32_f16(afrag[ks], b, acc[c], 0, 0, 0);
        }
    }
    float dv[4];
#pragma unroll
    for (int j = 0; j < 4; ++j) dv[j] = dinv[row0 + lhi * 4 + j];
#pragma unroll
    for (int c = 0; c < 8; ++c)
#pragma unroll
        for (int j = 0; j < 4; ++j) {
            float v = acc[c][j] * dv[j];
            C[(size_t)(row0 + lhi * 4 + j) * CH + c * 16 + l15] = (_Float16)v;
        }
}

// ---------------- Aggregation layer-1 (R4-proven, at path roofline) ----------------
// FETCH ~194 MB = compulsory (each XCD streams the 25.6 MB h-table once) at the
// ~3.5 TB/s random-line L2-miss/L3 path ceiling.

__global__ __launch_bounds__(256) void k_agg128h(const _Float16* __restrict__ h, const int* __restrict__ rp,
                                                 const int* __restrict__ col, const float* __restrict__ dinv,
                                                 const float* __restrict__ sc, const float* __restrict__ sh,
                                                 _Float16* __restrict__ out) {
    int node = blockIdx.x * 4 + (threadIdx.x >> 6);
    if (node >= NN) return;
    node = __builtin_amdgcn_readfirstlane(node);
    int lane = threadIdx.x & 63;
    int beg = rp[node], end = rp[node + 1];
    float ax = 0.f, ay = 0.f;
    int e = beg;
    for (; e + 8 <= end; e += 8) {
        int s0 = col[e], s1 = col[e + 1], s2 = col[e + 2], s3 = col[e + 3];
        int s4 = col[e + 4], s5 = col[e + 5], s6 = col[e + 6], s7 = col[e + 7];
        h2 v0 = *(const h2*)(h + (size_t)s0 * CH + lane * 2);
        h2 v1 = *(const h2*)(h + (size_t)s1 * CH + lane * 2);
        h2 v2 = *(const h2*)(h + (size_t)s2 * CH + lane * 2);
        h2 v3 = *(const h2*)(h + (size_t)s3 * CH + lane * 2);
        h2 v4 = *(const h2*)(h + (size_t)s4 * CH + lane * 2);
        h2 v5 = *(const h2*)(h + (size_t)s5 * CH + lane * 2);
        h2 v6 = *(const h2*)(h + (size_t)s6 * CH + lane * 2);
        h2 v7 = *(const h2*)(h + (size_t)s7 * CH + lane * 2);
        ax += ((float)v0[0] + (float)v1[0]) + ((float)v2[0] + (float)v3[0])
            + ((float)v4[0] + (float)v5[0]) + ((float)v6[0] + (float)v7[0]);
        ay += ((float)v0[1] + (float)v1[1]) + ((float)v2[1] + (float)v3[1])
            + ((float)v4[1] + (float)v5[1]) + ((float)v6[1] + (float)v7[1]);
    }
    if (e + 4 <= end) {
        int s0 = col[e], s1 = col[e + 1], s2 = col[e + 2], s3 = col[e + 3];
        h2 v0 = *(const h2*)(h + (size_t)s0 * CH + lane * 2);
        h2 v1 = *(const h2*)(h + (size_t)s1 * CH + lane * 2);
        h2 v2 = *(const h2*)(h + (size_t)s2 * CH + lane * 2);
        h2 v3 = *(const h2*)(h + (size_t)s3 * CH + lane * 2);
        ax += ((float)v0[0] + (float)v1[0]) + ((float)v2[0] + (float)v3[0]);
        ay += ((float)v0[1] + (float)v1[1]) + ((float)v2[1] + (float)v3[1]);
        e += 4;
    }
    for (; e < end; ++e) {
        int s0 = col[e];
        h2 v0 = *(const h2*)(h + (size_t)s0 * CH + lane * 2);
        ax += (float)v0[0];
        ay += (float)v0[1];
    }
    float dvn = dinv[node];
    int c = lane * 2;
    float2 scv = *(const float2*)(sc + c);
    float2 shv = *(const float2*)(sh + c);
    float o0 = fmaxf(fmaf(ax * dvn, scv.x, shv.x), 0.f);
    float o1 = fmaxf(fmaf(ay * dvn, scv.y, shv.y), 0.f);
    h2 o; o[0] = (_Float16)o0; o[1] = (_Float16)o1;
    *(h2*)(out + (size_t)node * CH + c) = o;
}

// ---------------- Aggregation layer-2 fused with W3 GEMV epilogue ----------------
// Same gather loop; epilogue computes H3[node] = (relu_bn_row . W3) * dinv[node]
// in-register (wave holds the full 128-ch row): 4 fma + 12 shfl-adds, writes 8 B
// instead of 256 B. Eliminates k_gemm_out (25.6 MB read) and agg2's 25 MB write.

__global__ __launch_bounds__(256) void k_agg_w3(const _Float16* __restrict__ h, const int* __restrict__ rp,
                                                const int* __restrict__ col, const float* __restrict__ dinv,
                                                const float* __restrict__ sc, const float* __restrict__ sh,
                                                const float* __restrict__ W3, float* __restrict__ H3) {
    int node = blockIdx.x * 4 + (threadIdx.x >> 6);
    if (node >= NN) return;
    node = __builtin_amdgcn_readfirstlane(node);
    int lane = threadIdx.x & 63;
    int beg = rp[node], end = rp[node + 1];
    float ax = 0.f, ay = 0.f;
    int e = beg;
    for (; e + 8 <= end; e += 8) {
        int s0 = col[e], s1 = col[e + 1], s2 = col[e + 2], s3 = col[e + 3];
        int s4 = col[e + 4], s5 = col[e + 5], s6 = col[e + 6], s7 = col[e + 7];
        h2 v0 = *(const h2*)(h + (size_t)s0 * CH + lane * 2);
        h2 v1 = *(const h2*)(h + (size_t)s1 * CH + lane * 2);
        h2 v2 = *(const h2*)(h + (size_t)s2 * CH + lane * 2);
        h2 v3 = *(const h2*)(h + (size_t)s3 * CH + lane * 2);
        h2 v4 = *(const h2*)(h + (size_t)s4 * CH + lane * 2);
        h2 v5 = *(const h2*)(h + (size_t)s5 * CH + lane * 2);
        h2 v6 = *(const h2*)(h + (size_t)s6 * CH + lane * 2);
        h2 v7 = *(const h2*)(h + (size_t)s7 * CH + lane * 2);
        ax += ((float)v0[0] + (float)v1[0]) + ((float)v2[0] + (float)v3[0])
            + ((float)v4[0] + (float)v5[0]) + ((float)v6[0] + (float)v7[0]);
        ay += ((float)v0[1] + (float)v1[1]) + ((float)v2[1] + (float)v3[1])
            + ((float)v4[1] + (float)v5[1]) + ((float)v6[1] + (float)v7[1]);
    }
    if (e + 4 <= end) {
        int s0 = col[e], s1 = col[e + 1], s2 = col[e + 2], s3 = col[e + 3];
        h2 v0 = *(const h2*)(h + (size_t)s0 * CH + lane * 2);
        h2 v1 = *(const h2*)(h + (size_t)s1 * CH + lane * 2);
        h2 v2 = *(const h2*)(h + (size_t)s2 * CH + lane * 2);
        h2 v3 = *(const h2*)(h + (size_t)s3 * CH + lane * 2);
        ax += ((float)v0[0] + (float)v1[0]) + ((float)v2[0] + (float)v3[0]);
        ay += ((float)v0[1] + (float)v1[1]) + ((float)v2[1] + (float)v3[1]);
        e += 4;
    }
    for (; e < end; ++e) {
        int s0 = col[e];
        h2 v0 = *(const h2*)(h + (size_t)s0 * CH + lane * 2);
        ax += (float)v0[0];
        ay += (float)v0[1];
    }
    float dvn = dinv[node];
    int c = lane * 2;
    float2 scv = *(const float2*)(sc + c);
    float2 shv = *(const float2*)(sh + c);
    float o0 = fmaxf(fmaf(ax * dvn, scv.x, shv.x), 0.f);
    float o1 = fmaxf(fmaf(ay * dvn, scv.y, shv.y), 0.f);
    // W3 GEMV: lane covers channels c, c+1. w = {W3[c][0],W3[c][1],W3[c+1][0],W3[c+1][1]}
    float4 w = *(const float4*)(W3 + c * 2);
    float a0 = fmaf(o1, w.z, o0 * w.x);
    float a1 = fmaf(o1, w.w, o0 * w.y);
#pragma unroll
    for (int off = 1; off < 64; off <<= 1) {
        a0 += __shfl_xor(a0, off);
        a1 += __shfl_xor(a1, off);
    }
    if (lane == 0)
        *(float2*)(H3 + (size_t)node * 2) = make_float2(a0 * dvn, a1 * dvn);
}

// ---------------- final edge-sum over 2-ch H3 + bias ----------------

__global__ __launch_bounds__(256) void k_agg_out(const float* __restrict__ H3, const int* __restrict__ rp,
                                                 const int* __restrict__ col, const float* __restrict__ dinv,
                                                 const float* __restrict__ b3, float* __restrict__ out) {
    int n = blockIdx.x * 256 + threadIdx.x;
    if (n >= NN) return;
    int beg = rp[n], end = rp[n + 1];
    float a0 = 0.f, a1 = 0.f;
    for (int e = beg; e < end; ++e) {
        int s = col[e];
        float2 hv = *(const float2*)(H3 + (size_t)s * 2);
        a0 += hv.x;
        a1 += hv.y;
    }
    float dv = dinv[n];
    out[(size_t)n * 2 + 0] = fmaf(a0, dv, b3[0]);
    out[(size_t)n * 2 + 1] = fmaf(a1, dv, b3[1]);
}

// ---------------- launch ----------------

extern "C" void kernel_launch(void* const* d_in, const int* in_sizes, int n_in,
                              void* d_out, int out_size, void* d_ws, size_t ws_size,
                              hipStream_t stream) {
    const float* x  = (const float*)d_in[0];
    const int* ei   = (const int*)d_in[1];
    const int* src  = ei;
    const int* dst  = ei + EE;
    const float* W1 = (const float*)d_in[2];
    const float* b1 = (const float*)d_in[3];
    const float* g1 = (const float*)d_in[4];
    const float* be1 = (const float*)d_in[5];
    const float* rm1 = (const float*)d_in[6];
    const float* rv1 = (const float*)d_in[7];
    const float* W2 = (const float*)d_in[8];
    const float* b2 = (const float*)d_in[9];
    const float* g2 = (const float*)d_in[10];
    const float* be2 = (const float*)d_in[11];
    const float* rm2 = (const float*)d_in[12];
    const float* rv2 = (const float*)d_in[13];
    const float* W3 = (const float*)d_in[14];
    const float* b3 = (const float*)d_in[15];
    float* out = (float*)d_out;

    char* p = (char*)d_ws;
    auto carve = [&](size_t bytes) -> void* {
        void* r = (void*)p;
        p += (bytes + 255) & ~(size_t)255;
        return r;
    };
    int* rp     = (int*)carve((size_t)(NN + 1) * 4);
    float* dinv = (float*)carve((size_t)NN * 4);
    int* col    = (int*)carve((size_t)(EE + NN) * 4);
    int* bbase  = (int*)carve(256 * 4);
    float* sc1  = (float*)carve(128 * 4);
    float* sh1  = (float*)carve(128 * 4);
    float* sc2  = (float*)carve(128 * 4);
    float* sh2  = (float*)carve(128 * 4);
    _Float16* bufA = (_Float16*)carve((size_t)NN * CH * 2);
    _Float16* bufB = (_Float16*)carve((size_t)NN * CH * 2);
    _Float16* Wt1  = (_Float16*)carve(128 * 128 * 2);
    _Float16* Wt2  = (_Float16*)carve(128 * 128 * 2);
    float* h3   = (float*)carve((size_t)NN * 2 * 4);

    // bucket workspace aliases bufA (dead until first GEMM): 8.03 MB < 25.6 MB
    int* eb   = (int*)bufA;
    int* gcur = eb + (size_t)NBUCK * CAP_E;

    hipMemsetAsync(gcur, 0, (size_t)NBUCK * 4, stream);

    k_passA<<<(EE + 4095) / 4096, 256, 0, stream>>>(src, dst, gcur, eb);
    k_bscan_prep<<<130, 256, 0, stream>>>(gcur, bbase, rp,
                                          W1, W2, Wt1, Wt2,
                                          b1, g1, be1, rm1, rv1,
                                          b2, g2, be2, rm2, rv2,
                                          sc1, sh1, sc2, sh2);
    k_passB<<<NBUCK, 256, 0, stream>>>(gcur, eb, bbase, rp, dinv, col);

    k_gemm_mfma<true><<<(NN + 63) / 64, 256, 0, stream>>>(x, Wt1, dinv, bufA);
    k_agg128h<<<(NN + 3) / 4, 256, 0, stream>>>(bufA, rp, col, dinv, sc1, sh1, bufB);
    k_gemm_mfma<false><<<(NN + 63) / 64, 256, 0, stream>>>(bufB, Wt2, dinv, bufA);
    k_agg_w3<<<(NN + 3) / 4, 256, 0, stream>>>(bufA, rp, col, dinv, sc2, sh2, W3, h3);
    k_agg_out<<<(NN + 255) / 256, 256, 0, stream>>>(h3, rp, col, dinv, b3, out);
}